// Round 19
// baseline (175.906 us; speedup 1.0000x reference)
//
#include <hip/hip_runtime.h>
#include <cstdint>
#include <cstddef>

// ---------------------------------------------------------------------------
// Problem: B=4, S=1024, D=1024, H=16, HD=64.
// out (B,S,D) f32 then prob (B,H,S,S) f32, concatenated in d_out.
// ---------------------------------------------------------------------------

typedef __bf16 bf16_t;
typedef __bf16 bf16x8 __attribute__((ext_vector_type(8)));
typedef __bf16 bf16x4 __attribute__((ext_vector_type(4)));
typedef float  f32x4  __attribute__((ext_vector_type(4)));

__device__ __forceinline__ f32x4 mfma16(bf16x8 a, bf16x8 b, f32x4 c) {
  return __builtin_amdgcn_mfma_f32_16x16x32_bf16(a, b, c, 0, 0, 0);
}

__device__ __forceinline__ void g2l16(const void* g, void* l) {
  __builtin_amdgcn_global_load_lds((__attribute__((address_space(1))) void*)(g),
                                   (__attribute__((address_space(3))) void*)(l),
                                   16, 0, 0);
}

// ---------------------------------------------------------------------------
// K1: FUSED cast + base (r18, measured −2.1 us).
//  blocks [0, 15360):    cast query,key,value + Wq,Wk,Wv to bf16
//  blocks [15360, 19456): base[b,q,k] = l1*rel_attn + (1-l1)*l2*time_attn
// ---------------------------------------------------------------------------
__global__ __launch_bounds__(256) void cast_base_kernel(
    const float* __restrict__ q, const float* __restrict__ k, const float* __restrict__ v,
    const float* __restrict__ wq, const float* __restrict__ wk, const float* __restrict__ wv,
    const float* __restrict__ rel, const float* __restrict__ ts,
    const float* __restrict__ l1p, const float* __restrict__ l2p,
    bf16_t* __restrict__ Xb, bf16_t* __restrict__ Wb, bf16_t* __restrict__ baseb) {
  const int bidx = blockIdx.x;
  if (bidx < 15360) {
    // ---- cast part ----
    int i = bidx * 256 + threadIdx.x;       // 0 .. 3,932,159 float4 chunks
    const float* src;
    bf16_t* dst;
    if (i < 3145728) {                      // 3 * 2^20 chunks of X
      int m = i >> 20;
      size_t o = (size_t)(i & 1048575) * 4;
      src = (m == 0) ? q : (m == 1) ? k : v;
      dst = Xb + (size_t)m * 4194304 + o;
      src += o;
    } else {
      int j = i - 3145728;                  // 3 * 2^18 chunks of W
      int m = j >> 18;
      size_t o = (size_t)(j & 262143) * 4;
      src = (m == 0) ? wq : (m == 1) ? wk : wv;
      dst = Wb + (size_t)m * 1048576 + o;
      src += o;
    }
    f32x4 f = *(const f32x4*)src;
    bf16x4 r;
    r[0] = (bf16_t)f[0]; r[1] = (bf16_t)f[1]; r[2] = (bf16_t)f[2]; r[3] = (bf16_t)f[3];
    *(bf16x4*)dst = r;
    return;
  }
  // ---- base part: one row b*1024+q per block ----
  const int row = bidx - 15360;        // b*1024 + q
  const int qq = row & 1023;
  const int tid = threadIdx.x;
  const int w = tid >> 6;
  const float l1 = *l1p, l2 = *l2p;
  const float cr = l1, ct = (1.f - l1) * l2;

  f32x4 rv = *(const f32x4*)(rel + (size_t)row * 1024 + tid * 4);
  f32x4 tv = *(const f32x4*)(ts  + (size_t)row * 1024 + tid * 4);

  float x[4], t[4];
  for (int j = 0; j < 4; ++j) {
    int kk = tid * 4 + j;
    bool msk = kk > qq;
    float rj = rv[j];
    x[j] = (msk || rj == 0.f) ? -100000.f : rj;
    t[j] = msk ? -1e9f : __expf(-fabsf(tv[j]));
  }
  float mr = fmaxf(fmaxf(x[0], x[1]), fmaxf(x[2], x[3]));
  float mt = fmaxf(fmaxf(t[0], t[1]), fmaxf(t[2], t[3]));
  for (int o = 1; o < 64; o <<= 1) {
    mr = fmaxf(mr, __shfl_xor(mr, o));
    mt = fmaxf(mt, __shfl_xor(mt, o));
  }
  __shared__ float red[4][4];
  if ((tid & 63) == 0) { red[0][w] = mr; red[1][w] = mt; }
  __syncthreads();
  mr = fmaxf(fmaxf(red[0][0], red[0][1]), fmaxf(red[0][2], red[0][3]));
  mt = fmaxf(fmaxf(red[1][0], red[1][1]), fmaxf(red[1][2], red[1][3]));

  float er[4], et[4], sr = 0.f, st = 0.f;
  for (int j = 0; j < 4; ++j) {
    er[j] = __expf(x[j] - mr);
    et[j] = __expf(t[j] - mt);
    sr += er[j]; st += et[j];
  }
  for (int o = 1; o < 64; o <<= 1) {
    sr += __shfl_xor(sr, o);
    st += __shfl_xor(st, o);
  }
  if ((tid & 63) == 0) { red[2][w] = sr; red[3][w] = st; }
  __syncthreads();
  sr = red[2][0] + red[2][1] + red[2][2] + red[2][3];
  st = red[3][0] + red[3][1] + red[3][2] + red[3][3];

  float isr = cr / sr, ist = ct / st;
  bf16x4 o4;
  for (int j = 0; j < 4; ++j) o4[j] = (bf16_t)(er[j] * isr + et[j] * ist);
  *(bf16x4*)(baseb + (size_t)row * 1024 + tid * 4) = o4;
}

// ---------------------------------------------------------------------------
// K2: Y[z] = X[z] @ W[z]^T + bias[z], bf16 in / bf16 out (f32 accum).
// BK=32 (r6 body), XCD-swizzled 1-D grid (768 blocks). z==2 epilogue writes
// vT[(b*16+h)*64+hd][s] DIRECTLY (fused V transpose, bf16x4 = 4 consecutive
// s per lane); Yb[2] never written, transpose_v kernel deleted.
// ---------------------------------------------------------------------------
__global__ __launch_bounds__(256) void gemm_qkv(
    const bf16_t* __restrict__ Xb, const bf16_t* __restrict__ Wb,
    const float* __restrict__ bqp, const float* __restrict__ bkp, const float* __restrict__ bvp,
    bf16_t* __restrict__ Yb, bf16_t* __restrict__ vT) {
  __shared__ __align__(16) bf16_t As[128 * 32];
  __shared__ __align__(16) bf16_t Bs[128 * 32];
  const int bid = blockIdx.x;
  const int xcd = bid & 7;
  const int j = bid >> 3;            // [0,96)
  const int z = j >> 5;              // [0,3)
  const int jj = j & 31;             // [0,32)
  const int row = xcd * 4 + (jj >> 3);  // XCD owns rows [xcd*4, xcd*4+4)
  const int col = jj & 7;            // col fastest -> X panel hot in L2
  const bf16_t* X = Xb + (size_t)z * 4194304;
  const bf16_t* W = Wb + (size_t)z * 1048576;
  const float* bias = (z == 0) ? bqp : (z == 1) ? bkp : bvp;
  bf16_t* Y = Yb + (size_t)z * 4194304;

  const int tid = threadIdx.x;
  const int lane = tid & 63;
  const int w = tid >> 6;
  const int wr = w >> 1, wc = w & 1;
  const int rb = row * 128, cb = col * 128;
  const int lr = lane & 15, g = lane >> 4;

  f32x4 zero = {0.f, 0.f, 0.f, 0.f};
  f32x4 acc[4][4];
  for (int m = 0; m < 4; ++m)
    for (int n = 0; n < 4; ++n) acc[m][n] = zero;

  for (int k0 = 0; k0 < 1024; k0 += 32) {
    for (int r = 0; r < 2; ++r) {
      int cid = r * 256 + tid;
      int rw = cid >> 2;
      int ko = (cid & 3) * 8;
      const bf16_t* ga = X + ((size_t)(rb + rw) * 1024 + k0 + ko);
      const bf16_t* gb = W + ((size_t)(cb + rw) * 1024 + k0 + ko);
      char* la = (char*)As + r * 4096 + w * 1024;   // wave-uniform base
      char* lb = (char*)Bs + r * 4096 + w * 1024;
      g2l16(ga, la);
      g2l16(gb, lb);
    }
    asm volatile("s_waitcnt vmcnt(0)" ::: "memory");
    __syncthreads();

    bf16x8 afr[4], bfr[4];
    for (int m = 0; m < 4; ++m)
      afr[m] = *(const bf16x8*)&As[(wr * 64 + m * 16 + lr) * 32 + g * 8];
    for (int n = 0; n < 4; ++n)
      bfr[n] = *(const bf16x8*)&Bs[(wc * 64 + n * 16 + lr) * 32 + g * 8];
    for (int m = 0; m < 4; ++m)
      for (int n = 0; n < 4; ++n)
        acc[m][n] = mfma16(afr[m], bfr[n], acc[m][n]);
    __syncthreads();
  }

  if (z == 2) {
    // fused V transpose: acc row index (r) is the s direction -> bf16x4 of
    // 4 consecutive s. vT[(b*16+h)*64+hd][s], lines covered within block.
    for (int m = 0; m < 4; ++m) {
      const int rowb = rb + wr * 64 + m * 16 + g * 4;   // = b*1024 + s0
      const int bb = rowb >> 10;
      const int s0 = rowb & 1023;
      for (int n = 0; n < 4; ++n) {
        const int colc = cb + wc * 64 + n * 16 + lr;    // = h*64 + hd
        const float bv = bias[colc];
        bf16x4 o;
        for (int r = 0; r < 4; ++r) o[r] = (bf16_t)(acc[m][n][r] + bv);
        *(bf16x4*)(vT + ((size_t)(bb * 16 + (colc >> 6)) * 64 + (colc & 63)) * 1024 + s0) = o;
      }
    }
  } else {
    for (int m = 0; m < 4; ++m) {
      const int rowb = rb + wr * 64 + m * 16 + g * 4;
      for (int n = 0; n < 4; ++n) {
        const int colc = cb + wc * 64 + n * 16 + lr;
        const float bv = bias[colc];
        for (int r = 0; r < 4; ++r)
          Y[(size_t)(rowb + r) * 1024 + colc] = (bf16_t)(acc[m][n][r] + bv);
      }
    }
  }
}

// ---------------------------------------------------------------------------
// K4: attention — r6/r14 structure + T5 setprio (measured neutral-to-equal).
// Block = 32 q-rows x (b,h); 8 waves = 2 row-tiles x 4 chunk-split waves.
// XCD-swizzled grid. grid 2048 blocks, 512 threads.
// ---------------------------------------------------------------------------
__global__ __launch_bounds__(512) void attn_kernel(
    const bf16_t* __restrict__ qY, const bf16_t* __restrict__ kY,
    const bf16_t* __restrict__ vT, const bf16_t* __restrict__ baseb,
    const float* __restrict__ l1p, const float* __restrict__ l2p,
    float* __restrict__ outp, float* __restrict__ probp) {
  const int bid = blockIdx.x;
  const int j = bid >> 3;
  const int bh = (bid & 7) * 8 + (j & 7);
  const int qg = 31 - (j >> 3);
  const int b = bh >> 4, h = bh & 15;
  const int q0 = qg * 32;
  const int tid = threadIdx.x, lane = tid & 63, w = tid >> 6;
  const int t = w >> 2;          // row-tile (0/1)
  const int cw = w & 3;          // chunk-split lane within row-tile
  const int lr = lane & 15, g = lane >> 4;
  const int qr = q0 + t * 16 + lr;
  const float l1 = *l1p, l2 = *l2p;
  const float c1 = (1.f - l1) * (1.f - l2);

  __shared__ __align__(16) union ShMem {
    bf16_t plds[8][16][36];
    float  pvred[8][16][64];
  } sh;
  __shared__ float zred[8][16];

  const bf16_t* qbase = qY + ((size_t)(b * 1024 + qr)) * 1024 + h * 64 + g * 8;
  bf16x8 bq0 = *(const bf16x8*)qbase;
  bf16x8 bq1 = *(const bf16x8*)(qbase + 32);

  const bf16_t* kptr = kY + ((size_t)(b * 1024 + lr)) * 1024 + h * 64 + g * 8;

  const int nch = (q0 + t * 16) / 32 + 1;
  f32x4 zero = {0.f, 0.f, 0.f, 0.f};

  // ---- pass 1: Z = row sums of exp; cache e (bf16) in registers ----
  bf16x4 esave[8][2];
  float zp = 0.f;
#pragma unroll
  for (int c = 0; c < 8; ++c) {
    const int ch = cw + 4 * c;
    if (ch < nch) {
      const bf16_t* p0 = kptr + (size_t)ch * 32768;
      bf16x8 k0 = *(const bf16x8*)p0;
      bf16x8 k1 = *(const bf16x8*)(p0 + 32);
      bf16x8 k2 = *(const bf16x8*)(p0 + 16384);
      bf16x8 k3 = *(const bf16x8*)(p0 + 16416);
      f32x4 s0 = zero, s1 = zero;
      __builtin_amdgcn_s_setprio(1);
      s0 = mfma16(k0, bq0, s0);
      s0 = mfma16(k1, bq1, s0);
      s1 = mfma16(k2, bq0, s1);
      s1 = mfma16(k3, bq1, s1);
      __builtin_amdgcn_s_setprio(0);
      const int kc0 = ch * 32 + g * 4;
      bf16x4 e0, e1;
      for (int r = 0; r < 4; ++r) {
        float ea = (kc0 + r > qr) ? 0.f : __expf(s0[r] * 0.125f);
        float eb = (kc0 + 16 + r > qr) ? 0.f : __expf(s1[r] * 0.125f);
        zp += ea + eb;
        e0[r] = (bf16_t)ea;
        e1[r] = (bf16_t)eb;
      }
      esave[c][0] = e0;
      esave[c][1] = e1;
    }
  }
  zp += __shfl_xor(zp, 16);
  zp += __shfl_xor(zp, 32);
  if (lane < 16) zred[w][lr] = zp;
  __syncthreads();
  const float Z = zred[t * 4 + 0][lr] + zred[t * 4 + 1][lr] +
                  zred[t * 4 + 2][lr] + zred[t * 4 + 3][lr];
  const float invz = c1 / Z;

  // ---- pass 2: prob (coalesced NT store via plds) + partial P@V ----
  const bf16_t* baserow = baseb + ((size_t)(b * 1024 + qr)) * 1024;
  const bf16_t* vbase = vT + ((size_t)(bh * 64 + lr)) * 1024 + g * 8;
  float* probbase = probp + ((size_t)(bh * 1024 + q0 + t * 16)) * 1024;
  const int srow = lane >> 3, scol = (lane & 7) * 4;

  f32x4 acc[4];
  for (int cf = 0; cf < 4; ++cf) acc[cf] = zero;

#pragma unroll
  for (int c = 0; c < 8; ++c) {
    const int ch = cw + 4 * c;
    if (ch < nch) {
      bf16x8 vv[4];
      for (int cf = 0; cf < 4; ++cf)
        vv[cf] = *(const bf16x8*)(vbase + (size_t)cf * 16384 + ch * 32);
      for (int f = 0; f < 2; ++f) {
        const int kc0 = ch * 32 + f * 16 + g * 4;
        bf16x4 b4 = *(const bf16x4*)(baserow + kc0);
        bf16x4 eb = esave[c][f];
        bf16x4 pb;
        for (int r = 0; r < 4; ++r)
          pb[r] = (bf16_t)((float)eb[r] * invz + (float)b4[r]);
        *(bf16x4*)&sh.plds[w][lr][f * 16 + g * 4] = pb;
      }
      asm volatile("s_waitcnt lgkmcnt(0)" ::: "memory");
      bf16x8 pa = *(const bf16x8*)&sh.plds[w][lr][g * 8];
      // coalesced prob store: 2 instructions x (8 rows x full 128B line)
      bf16x4 r0 = *(const bf16x4*)&sh.plds[w][srow][scol];
      bf16x4 r1 = *(const bf16x4*)&sh.plds[w][srow + 8][scol];
      f32x4 o0, o1;
      for (int jj = 0; jj < 4; ++jj) { o0[jj] = (float)r0[jj]; o1[jj] = (float)r1[jj]; }
      float* pr = probbase + (size_t)srow * 1024 + ch * 32 + scol;
      __builtin_nontemporal_store(o0, (f32x4*)pr);
      __builtin_nontemporal_store(o1, (f32x4*)(pr + 8 * 1024));
      __builtin_amdgcn_s_setprio(1);
      for (int cf = 0; cf < 4; ++cf)
        acc[cf] = mfma16(pa, vv[cf], acc[cf]);
      __builtin_amdgcn_s_setprio(0);
    }
  }

  // ---- tail: fully masked chunks -> prob = base (4 rows per wave) ----
  const int kstart = nch * 32;
  for (int i = 0; i < 4; ++i) {
    int qrr = q0 + t * 16 + cw * 4 + i;
    const bf16_t* brow = baseb + ((size_t)(b * 1024 + qrr)) * 1024;
    float* prow = probp + ((size_t)(bh * 1024 + qrr)) * 1024;
    for (int k = kstart + lane * 4; k < 1024; k += 256) {
      bf16x4 b4 = *(const bf16x4*)(brow + k);
      f32x4 f4;
      f4[0] = (float)b4[0]; f4[1] = (float)b4[1];
      f4[2] = (float)b4[2]; f4[3] = (float)b4[3];
      __builtin_nontemporal_store(f4, (f32x4*)(prow + k));
    }
  }

  // ---- PV cross-wave combine + out store ----
  __syncthreads();                    // all waves done with plds
  for (int cf = 0; cf < 4; ++cf)
    for (int r = 0; r < 4; ++r)
      sh.pvred[w][g * 4 + r][cf * 16 + lr] = acc[cf][r];
  __syncthreads();
  {
    const int gw = tid >> 6, hd = tid & 63;
    const int tt = gw >> 2;
    for (int i = 0; i < 4; ++i) {
      int rr = (gw & 3) * 4 + i;
      float s = sh.pvred[tt * 4 + 0][rr][hd] + sh.pvred[tt * 4 + 1][rr][hd] +
                sh.pvred[tt * 4 + 2][rr][hd] + sh.pvred[tt * 4 + 3][rr][hd];
      outp[((size_t)(b * 1024 + q0 + tt * 16 + rr)) * 1024 + h * 64 + hd] = s;
    }
  }
}

// ---------------------------------------------------------------------------
extern "C" void kernel_launch(void* const* d_in, const int* in_sizes, int n_in,
                              void* d_out, int out_size, void* d_ws, size_t ws_size,
                              hipStream_t stream) {
  const float* query = (const float*)d_in[0];
  const float* key   = (const float*)d_in[1];
  const float* value = (const float*)d_in[2];
  const float* rel   = (const float*)d_in[3];
  const float* l1p   = (const float*)d_in[4];
  const float* l2p   = (const float*)d_in[5];
  const float* tsp   = (const float*)d_in[6];
  const float* Wq = (const float*)d_in[11];
  const float* bq = (const float*)d_in[12];
  const float* Wk = (const float*)d_in[13];
  const float* bk = (const float*)d_in[14];
  const float* Wv = (const float*)d_in[15];
  const float* bv = (const float*)d_in[16];

  char* ws = (char*)d_ws;
  bf16_t* Xb    = (bf16_t*)(ws);              // 3 x 4096x1024 bf16
  bf16_t* Wb    = (bf16_t*)(ws + 25165824);   // 3 x 1024x1024 bf16
  bf16_t* Yb    = (bf16_t*)(ws + 31457280);   // 3 x 4096x1024 bf16 (z=2 unused)
  bf16_t* vT    = (bf16_t*)(ws + 56623104);   // 64 x 64 x 1024 bf16
  bf16_t* baseb = (bf16_t*)(ws + 65011712);   // 4096 x 1024 bf16

  float* outp  = (float*)d_out;
  float* probp = outp + 4194304;

  cast_base_kernel<<<dim3(19456), dim3(256), 0, stream>>>(
      query, key, value, Wq, Wk, Wv, rel, tsp, l1p, l2p, Xb, Wb, baseb);
  gemm_qkv<<<dim3(768), dim3(256), 0, stream>>>(Xb, Wb, bq, bk, bv, Yb, vT);
  attn_kernel<<<dim3(2048), dim3(512), 0, stream>>>(Yb, Yb + 4194304, vT, baseb,
                                                    l1p, l2p, outp, probp);
}

// Round 20
// 166.228 us; speedup vs baseline: 1.0582x; 1.0582x over previous
//
#include <hip/hip_runtime.h>
#include <cstdint>
#include <cstddef>

// ---------------------------------------------------------------------------
// Problem: B=4, S=1024, D=1024, H=16, HD=64.
// out (B,S,D) f32 then prob (B,H,S,S) f32, concatenated in d_out.
// Final configuration (r18, best measured 166.3 us):
//   K1 fused cast+base -> K2 gemm (XCD-swizzled) -> K2b transpose_v -> K4 attn
// ---------------------------------------------------------------------------

typedef __bf16 bf16_t;
typedef __bf16 bf16x8 __attribute__((ext_vector_type(8)));
typedef __bf16 bf16x4 __attribute__((ext_vector_type(4)));
typedef float  f32x4  __attribute__((ext_vector_type(4)));

__device__ __forceinline__ f32x4 mfma16(bf16x8 a, bf16x8 b, f32x4 c) {
  return __builtin_amdgcn_mfma_f32_16x16x32_bf16(a, b, c, 0, 0, 0);
}

__device__ __forceinline__ void g2l16(const void* g, void* l) {
  __builtin_amdgcn_global_load_lds((__attribute__((address_space(1))) void*)(g),
                                   (__attribute__((address_space(3))) void*)(l),
                                   16, 0, 0);
}

// ---------------------------------------------------------------------------
// K1: FUSED cast + base.
//  blocks [0, 15360):    cast query,key,value + Wq,Wk,Wv to bf16
//  blocks [15360, 19456): base[b,q,k] = l1*rel_attn + (1-l1)*l2*time_attn
// ---------------------------------------------------------------------------
__global__ __launch_bounds__(256) void cast_base_kernel(
    const float* __restrict__ q, const float* __restrict__ k, const float* __restrict__ v,
    const float* __restrict__ wq, const float* __restrict__ wk, const float* __restrict__ wv,
    const float* __restrict__ rel, const float* __restrict__ ts,
    const float* __restrict__ l1p, const float* __restrict__ l2p,
    bf16_t* __restrict__ Xb, bf16_t* __restrict__ Wb, bf16_t* __restrict__ baseb) {
  const int bidx = blockIdx.x;
  if (bidx < 15360) {
    // ---- cast part ----
    int i = bidx * 256 + threadIdx.x;       // 0 .. 3,932,159 float4 chunks
    const float* src;
    bf16_t* dst;
    if (i < 3145728) {                      // 3 * 2^20 chunks of X
      int m = i >> 20;
      size_t o = (size_t)(i & 1048575) * 4;
      src = (m == 0) ? q : (m == 1) ? k : v;
      dst = Xb + (size_t)m * 4194304 + o;
      src += o;
    } else {
      int j = i - 3145728;                  // 3 * 2^18 chunks of W
      int m = j >> 18;
      size_t o = (size_t)(j & 262143) * 4;
      src = (m == 0) ? wq : (m == 1) ? wk : wv;
      dst = Wb + (size_t)m * 1048576 + o;
      src += o;
    }
    f32x4 f = *(const f32x4*)src;
    bf16x4 r;
    r[0] = (bf16_t)f[0]; r[1] = (bf16_t)f[1]; r[2] = (bf16_t)f[2]; r[3] = (bf16_t)f[3];
    *(bf16x4*)dst = r;
    return;
  }
  // ---- base part: one row b*1024+q per block ----
  const int row = bidx - 15360;        // b*1024 + q
  const int qq = row & 1023;
  const int tid = threadIdx.x;
  const int w = tid >> 6;
  const float l1 = *l1p, l2 = *l2p;
  const float cr = l1, ct = (1.f - l1) * l2;

  f32x4 rv = *(const f32x4*)(rel + (size_t)row * 1024 + tid * 4);
  f32x4 tv = *(const f32x4*)(ts  + (size_t)row * 1024 + tid * 4);

  float x[4], t[4];
  for (int j = 0; j < 4; ++j) {
    int kk = tid * 4 + j;
    bool msk = kk > qq;
    float rj = rv[j];
    x[j] = (msk || rj == 0.f) ? -100000.f : rj;
    t[j] = msk ? -1e9f : __expf(-fabsf(tv[j]));
  }
  float mr = fmaxf(fmaxf(x[0], x[1]), fmaxf(x[2], x[3]));
  float mt = fmaxf(fmaxf(t[0], t[1]), fmaxf(t[2], t[3]));
  for (int o = 1; o < 64; o <<= 1) {
    mr = fmaxf(mr, __shfl_xor(mr, o));
    mt = fmaxf(mt, __shfl_xor(mt, o));
  }
  __shared__ float red[4][4];
  if ((tid & 63) == 0) { red[0][w] = mr; red[1][w] = mt; }
  __syncthreads();
  mr = fmaxf(fmaxf(red[0][0], red[0][1]), fmaxf(red[0][2], red[0][3]));
  mt = fmaxf(fmaxf(red[1][0], red[1][1]), fmaxf(red[1][2], red[1][3]));

  float er[4], et[4], sr = 0.f, st = 0.f;
  for (int j = 0; j < 4; ++j) {
    er[j] = __expf(x[j] - mr);
    et[j] = __expf(t[j] - mt);
    sr += er[j]; st += et[j];
  }
  for (int o = 1; o < 64; o <<= 1) {
    sr += __shfl_xor(sr, o);
    st += __shfl_xor(st, o);
  }
  if ((tid & 63) == 0) { red[2][w] = sr; red[3][w] = st; }
  __syncthreads();
  sr = red[2][0] + red[2][1] + red[2][2] + red[2][3];
  st = red[3][0] + red[3][1] + red[3][2] + red[3][3];

  float isr = cr / sr, ist = ct / st;
  bf16x4 o4;
  for (int j = 0; j < 4; ++j) o4[j] = (bf16_t)(er[j] * isr + et[j] * ist);
  *(bf16x4*)(baseb + (size_t)row * 1024 + tid * 4) = o4;
}

// ---------------------------------------------------------------------------
// K2: Y[z] = X[z] @ W[z]^T + bias[z], bf16 in / bf16 out (f32 accum).
// BK=32, XCD-swizzled 1-D grid (768 blocks): xcd = bid&7 owns 4 row-panels
// x 8 cols per z -> per-XCD L2 set = 1MB X + 2MB W, X panel reused 8x hot.
// ---------------------------------------------------------------------------
__global__ __launch_bounds__(256) void gemm_qkv(
    const bf16_t* __restrict__ Xb, const bf16_t* __restrict__ Wb,
    const float* __restrict__ bqp, const float* __restrict__ bkp, const float* __restrict__ bvp,
    bf16_t* __restrict__ Yb) {
  __shared__ __align__(16) bf16_t As[128 * 32];
  __shared__ __align__(16) bf16_t Bs[128 * 32];
  const int bid = blockIdx.x;
  const int xcd = bid & 7;
  const int j = bid >> 3;            // [0,96)
  const int z = j >> 5;              // [0,3)
  const int jj = j & 31;             // [0,32)
  const int row = xcd * 4 + (jj >> 3);  // XCD owns rows [xcd*4, xcd*4+4)
  const int col = jj & 7;            // col fastest -> X panel hot in L2
  const bf16_t* X = Xb + (size_t)z * 4194304;
  const bf16_t* W = Wb + (size_t)z * 1048576;
  const float* bias = (z == 0) ? bqp : (z == 1) ? bkp : bvp;
  bf16_t* Y = Yb + (size_t)z * 4194304;

  const int tid = threadIdx.x;
  const int lane = tid & 63;
  const int w = tid >> 6;
  const int wr = w >> 1, wc = w & 1;
  const int rb = row * 128, cb = col * 128;
  const int lr = lane & 15, g = lane >> 4;

  f32x4 zero = {0.f, 0.f, 0.f, 0.f};
  f32x4 acc[4][4];
  for (int m = 0; m < 4; ++m)
    for (int n = 0; n < 4; ++n) acc[m][n] = zero;

  for (int k0 = 0; k0 < 1024; k0 += 32) {
    for (int r = 0; r < 2; ++r) {
      int cid = r * 256 + tid;
      int rw = cid >> 2;
      int ko = (cid & 3) * 8;
      const bf16_t* ga = X + ((size_t)(rb + rw) * 1024 + k0 + ko);
      const bf16_t* gb = W + ((size_t)(cb + rw) * 1024 + k0 + ko);
      char* la = (char*)As + r * 4096 + w * 1024;   // wave-uniform base
      char* lb = (char*)Bs + r * 4096 + w * 1024;
      g2l16(ga, la);
      g2l16(gb, lb);
    }
    asm volatile("s_waitcnt vmcnt(0)" ::: "memory");
    __syncthreads();

    bf16x8 afr[4], bfr[4];
    for (int m = 0; m < 4; ++m)
      afr[m] = *(const bf16x8*)&As[(wr * 64 + m * 16 + lr) * 32 + g * 8];
    for (int n = 0; n < 4; ++n)
      bfr[n] = *(const bf16x8*)&Bs[(wc * 64 + n * 16 + lr) * 32 + g * 8];
    for (int m = 0; m < 4; ++m)
      for (int n = 0; n < 4; ++n)
        acc[m][n] = mfma16(afr[m], bfr[n], acc[m][n]);
    __syncthreads();
  }

  for (int m = 0; m < 4; ++m) {
    int rowb = rb + wr * 64 + m * 16 + g * 4;
    for (int n = 0; n < 4; ++n) {
      int colc = cb + wc * 64 + n * 16 + lr;
      float bb = bias[colc];
      for (int r = 0; r < 4; ++r)
        Y[(size_t)(rowb + r) * 1024 + colc] = (bf16_t)(acc[m][n][r] + bb);
    }
  }
}

// ---------------------------------------------------------------------------
// K2b: transpose V: Yv (b*S+s, h*64+hd) -> vT (bh, hd, s)
// ---------------------------------------------------------------------------
__global__ __launch_bounds__(256) void transpose_v(const bf16_t* __restrict__ Yv,
                                                   bf16_t* __restrict__ vT) {
  __shared__ __align__(16) bf16_t t[64][68];
  const int bh = blockIdx.y, b = bh >> 4, h = bh & 15;
  const int s0 = blockIdx.x * 64;
  const int tid = threadIdx.x;
  for (int i = 0; i < 4; ++i) {
    int c = tid + i * 256;             // 0..1023
    int r = c >> 4, c4 = (c & 15) * 4; // row s, 4 hd's
    bf16x4 v4 = *(const bf16x4*)(Yv + ((size_t)(b * 1024 + s0 + r)) * 1024 + h * 64 + c4);
    *(bf16x4*)&t[r][c4] = v4;
  }
  __syncthreads();
  for (int i = 0; i < 4; ++i) {
    int c = tid + i * 256;
    int hd = c >> 4, s4 = (c & 15) * 4;
    bf16x4 o;
    o[0] = t[s4 + 0][hd]; o[1] = t[s4 + 1][hd];
    o[2] = t[s4 + 2][hd]; o[3] = t[s4 + 3][hd];
    *(bf16x4*)(vT + ((size_t)(bh * 64 + hd)) * 1024 + s0 + s4) = o;
  }
}

// ---------------------------------------------------------------------------
// K4: attention — r6 structure + T5 setprio (measured neutral-to-equal).
// Block = 32 q-rows x (b,h); 8 waves = 2 row-tiles x 4 chunk-split waves.
// XCD-swizzled grid. grid 2048 blocks, 512 threads.
// ---------------------------------------------------------------------------
__global__ __launch_bounds__(512) void attn_kernel(
    const bf16_t* __restrict__ qY, const bf16_t* __restrict__ kY,
    const bf16_t* __restrict__ vT, const bf16_t* __restrict__ baseb,
    const float* __restrict__ l1p, const float* __restrict__ l2p,
    float* __restrict__ outp, float* __restrict__ probp) {
  const int bid = blockIdx.x;
  const int j = bid >> 3;
  const int bh = (bid & 7) * 8 + (j & 7);
  const int qg = 31 - (j >> 3);
  const int b = bh >> 4, h = bh & 15;
  const int q0 = qg * 32;
  const int tid = threadIdx.x, lane = tid & 63, w = tid >> 6;
  const int t = w >> 2;          // row-tile (0/1)
  const int cw = w & 3;          // chunk-split lane within row-tile
  const int lr = lane & 15, g = lane >> 4;
  const int qr = q0 + t * 16 + lr;
  const float l1 = *l1p, l2 = *l2p;
  const float c1 = (1.f - l1) * (1.f - l2);

  __shared__ __align__(16) union ShMem {
    bf16_t plds[8][16][36];
    float  pvred[8][16][64];
  } sh;
  __shared__ float zred[8][16];

  const bf16_t* qbase = qY + ((size_t)(b * 1024 + qr)) * 1024 + h * 64 + g * 8;
  bf16x8 bq0 = *(const bf16x8*)qbase;
  bf16x8 bq1 = *(const bf16x8*)(qbase + 32);

  const bf16_t* kptr = kY + ((size_t)(b * 1024 + lr)) * 1024 + h * 64 + g * 8;

  const int nch = (q0 + t * 16) / 32 + 1;
  f32x4 zero = {0.f, 0.f, 0.f, 0.f};

  // ---- pass 1: Z = row sums of exp; cache e (bf16) in registers ----
  bf16x4 esave[8][2];
  float zp = 0.f;
#pragma unroll
  for (int c = 0; c < 8; ++c) {
    const int ch = cw + 4 * c;
    if (ch < nch) {
      const bf16_t* p0 = kptr + (size_t)ch * 32768;
      bf16x8 k0 = *(const bf16x8*)p0;
      bf16x8 k1 = *(const bf16x8*)(p0 + 32);
      bf16x8 k2 = *(const bf16x8*)(p0 + 16384);
      bf16x8 k3 = *(const bf16x8*)(p0 + 16416);
      f32x4 s0 = zero, s1 = zero;
      __builtin_amdgcn_s_setprio(1);
      s0 = mfma16(k0, bq0, s0);
      s0 = mfma16(k1, bq1, s0);
      s1 = mfma16(k2, bq0, s1);
      s1 = mfma16(k3, bq1, s1);
      __builtin_amdgcn_s_setprio(0);
      const int kc0 = ch * 32 + g * 4;
      bf16x4 e0, e1;
      for (int r = 0; r < 4; ++r) {
        float ea = (kc0 + r > qr) ? 0.f : __expf(s0[r] * 0.125f);
        float eb = (kc0 + 16 + r > qr) ? 0.f : __expf(s1[r] * 0.125f);
        zp += ea + eb;
        e0[r] = (bf16_t)ea;
        e1[r] = (bf16_t)eb;
      }
      esave[c][0] = e0;
      esave[c][1] = e1;
    }
  }
  zp += __shfl_xor(zp, 16);
  zp += __shfl_xor(zp, 32);
  if (lane < 16) zred[w][lr] = zp;
  __syncthreads();
  const float Z = zred[t * 4 + 0][lr] + zred[t * 4 + 1][lr] +
                  zred[t * 4 + 2][lr] + zred[t * 4 + 3][lr];
  const float invz = c1 / Z;

  // ---- pass 2: prob (coalesced NT store via plds) + partial P@V ----
  const bf16_t* baserow = baseb + ((size_t)(b * 1024 + qr)) * 1024;
  const bf16_t* vbase = vT + ((size_t)(bh * 64 + lr)) * 1024 + g * 8;
  float* probbase = probp + ((size_t)(bh * 1024 + q0 + t * 16)) * 1024;
  const int srow = lane >> 3, scol = (lane & 7) * 4;

  f32x4 acc[4];
  for (int cf = 0; cf < 4; ++cf) acc[cf] = zero;

#pragma unroll
  for (int c = 0; c < 8; ++c) {
    const int ch = cw + 4 * c;
    if (ch < nch) {
      bf16x8 vv[4];
      for (int cf = 0; cf < 4; ++cf)
        vv[cf] = *(const bf16x8*)(vbase + (size_t)cf * 16384 + ch * 32);
      for (int f = 0; f < 2; ++f) {
        const int kc0 = ch * 32 + f * 16 + g * 4;
        bf16x4 b4 = *(const bf16x4*)(baserow + kc0);
        bf16x4 eb = esave[c][f];
        bf16x4 pb;
        for (int r = 0; r < 4; ++r)
          pb[r] = (bf16_t)((float)eb[r] * invz + (float)b4[r]);
        *(bf16x4*)&sh.plds[w][lr][f * 16 + g * 4] = pb;
      }
      asm volatile("s_waitcnt lgkmcnt(0)" ::: "memory");
      bf16x8 pa = *(const bf16x8*)&sh.plds[w][lr][g * 8];
      // coalesced prob store: 2 instructions x (8 rows x full 128B line)
      bf16x4 r0 = *(const bf16x4*)&sh.plds[w][srow][scol];
      bf16x4 r1 = *(const bf16x4*)&sh.plds[w][srow + 8][scol];
      f32x4 o0, o1;
      for (int jj = 0; jj < 4; ++jj) { o0[jj] = (float)r0[jj]; o1[jj] = (float)r1[jj]; }
      float* pr = probbase + (size_t)srow * 1024 + ch * 32 + scol;
      __builtin_nontemporal_store(o0, (f32x4*)pr);
      __builtin_nontemporal_store(o1, (f32x4*)(pr + 8 * 1024));
      __builtin_amdgcn_s_setprio(1);
      for (int cf = 0; cf < 4; ++cf)
        acc[cf] = mfma16(pa, vv[cf], acc[cf]);
      __builtin_amdgcn_s_setprio(0);
    }
  }

  // ---- tail: fully masked chunks -> prob = base (4 rows per wave) ----
  const int kstart = nch * 32;
  for (int i = 0; i < 4; ++i) {
    int qrr = q0 + t * 16 + cw * 4 + i;
    const bf16_t* brow = baseb + ((size_t)(b * 1024 + qrr)) * 1024;
    float* prow = probp + ((size_t)(bh * 1024 + qrr)) * 1024;
    for (int k = kstart + lane * 4; k < 1024; k += 256) {
      bf16x4 b4 = *(const bf16x4*)(brow + k);
      f32x4 f4;
      f4[0] = (float)b4[0]; f4[1] = (float)b4[1];
      f4[2] = (float)b4[2]; f4[3] = (float)b4[3];
      __builtin_nontemporal_store(f4, (f32x4*)(prow + k));
    }
  }

  // ---- PV cross-wave combine + out store ----
  __syncthreads();                    // all waves done with plds
  for (int cf = 0; cf < 4; ++cf)
    for (int r = 0; r < 4; ++r)
      sh.pvred[w][g * 4 + r][cf * 16 + lr] = acc[cf][r];
  __syncthreads();
  {
    const int gw = tid >> 6, hd = tid & 63;
    const int tt = gw >> 2;
    for (int i = 0; i < 4; ++i) {
      int rr = (gw & 3) * 4 + i;
      float s = sh.pvred[tt * 4 + 0][rr][hd] + sh.pvred[tt * 4 + 1][rr][hd] +
                sh.pvred[tt * 4 + 2][rr][hd] + sh.pvred[tt * 4 + 3][rr][hd];
      outp[((size_t)(b * 1024 + q0 + tt * 16 + rr)) * 1024 + h * 64 + hd] = s;
    }
  }
}

// ---------------------------------------------------------------------------
extern "C" void kernel_launch(void* const* d_in, const int* in_sizes, int n_in,
                              void* d_out, int out_size, void* d_ws, size_t ws_size,
                              hipStream_t stream) {
  const float* query = (const float*)d_in[0];
  const float* key   = (const float*)d_in[1];
  const float* value = (const float*)d_in[2];
  const float* rel   = (const float*)d_in[3];
  const float* l1p   = (const float*)d_in[4];
  const float* l2p   = (const float*)d_in[5];
  const float* tsp   = (const float*)d_in[6];
  const float* Wq = (const float*)d_in[11];
  const float* bq = (const float*)d_in[12];
  const float* Wk = (const float*)d_in[13];
  const float* bk = (const float*)d_in[14];
  const float* Wv = (const float*)d_in[15];
  const float* bv = (const float*)d_in[16];

  char* ws = (char*)d_ws;
  bf16_t* Xb    = (bf16_t*)(ws);              // 3 x 4096x1024 bf16
  bf16_t* Wb    = (bf16_t*)(ws + 25165824);   // 3 x 1024x1024 bf16
  bf16_t* Yb    = (bf16_t*)(ws + 31457280);   // 3 x 4096x1024 bf16
  bf16_t* vT    = (bf16_t*)(ws + 56623104);   // 64 x 64 x 1024 bf16
  bf16_t* baseb = (bf16_t*)(ws + 65011712);   // 4096 x 1024 bf16

  float* outp  = (float*)d_out;
  float* probp = outp + 4194304;

  cast_base_kernel<<<dim3(19456), dim3(256), 0, stream>>>(
      query, key, value, Wq, Wk, Wv, rel, tsp, l1p, l2p, Xb, Wb, baseb);
  gemm_qkv<<<dim3(768), dim3(256), 0, stream>>>(Xb, Wb, bq, bk, bv, Yb);
  transpose_v<<<dim3(16, 64), dim3(256), 0, stream>>>(Yb + (size_t)2 * 4194304, vT);
  attn_kernel<<<dim3(2048), dim3(512), 0, stream>>>(Yb, Yb + 4194304, vT, baseb,
                                                    l1p, l2p, outp, probp);
}